// Round 10
// baseline (239.711 us; speedup 1.0000x reference)
//
#include <hip/hip_runtime.h>
#include <hip/hip_bf16.h>

// SubQAttention: B=4, H=16, T=1024, D=64, N_BINS=16, ROUTER_HIDDEN=128
// Fast path (ws >= 33.3MB):
//   prep_kernel : blocks 0-511 router -> probs; blocks 512-1535 convert
//                 K -> (Khi,Klo) [key][d] and V^T -> (VThi,VTlo) [d][key],
//                 bf16 hi/lo split, PRE-SWIZZLED per 64-tile (byte ^= (row&7)<<4)
//   mask_v3     : bucket&causal bitmask [B*T,16] u64
//   attn_bf16   : MFMA flash attention; staging = linear copy of preconverted
//                 tiles (no cvt in loop); QK^T 3-term split, PV 2-term (P_hi only)
// Fallback (small ws): round-9 attn_mfma (in-kernel cvt, 3-term PV).

#define B_ 4
#define H_ 16
#define T_ 1024
#define D_ 64
#define NB 16
#define RH 128

typedef __attribute__((ext_vector_type(8))) short s16x8;
typedef __attribute__((ext_vector_type(4))) float f32x4;

__device__ __forceinline__ unsigned short f2bf(float x) {  // HW RNE cast
  union { __hip_bfloat16 b; unsigned short u; } c;
  c.b = __hip_bfloat16(x);
  return c.u;
}
__device__ __forceinline__ float bf2f(unsigned short h) {
  return __uint_as_float(((unsigned)h) << 16);
}

// ---------------- prep: router (blocks 0-511) + K/V cvt (512-1535) ---------
__global__ __launch_bounds__(256) void prep_kernel(
    const float* __restrict__ kin, const float* __restrict__ vin,
    const float* __restrict__ W1, const float* __restrict__ b1,
    const float* __restrict__ W2, const float* __restrict__ b2,
    float* __restrict__ probs,
    unsigned short* __restrict__ khi, unsigned short* __restrict__ klo,
    unsigned short* __restrict__ vthi, unsigned short* __restrict__ vtlo) {
  __shared__ union {
    struct {
      float rows[8][1024];
      float part[8][8][RH];
      float hid[8][RH + 4];
      float logits[8][NB];
    } r;
    float vt[64][68];  // padded: transpose reads 2-way-bank only
  } sm;
  const int tid = threadIdx.x;

  if (blockIdx.x < 512) {  // ======== router (identical math to round 9) ====
    const int bb = blockIdx.x;
    const int b = bb >> 7;
    const int t0 = (bb & 127) << 3;

#pragma unroll
    for (int s = 0; s < 8; s++) {
      const int idx4 = tid + 256 * s;
      const int r = idx4 >> 8, i = (idx4 & 255) * 4;
      const int h = i >> 6, d = i & 63;
      *(float4*)&sm.r.rows[r][i] =
          *(const float4*)&kin[(((size_t)(b * H_) + h) * T_ + (t0 + r)) * D_ + d];
    }
    __syncthreads();

    const int hu0 = (tid & 31) << 2;
    const int k0 = (tid >> 5) << 7;
    float acc[8][4];
#pragma unroll
    for (int r = 0; r < 8; r++)
#pragma unroll
      for (int c = 0; c < 4; c++) acc[r][c] = 0.0f;

    for (int kb = 0; kb < 128; kb += 4) {
      float4 rv[8];
#pragma unroll
      for (int r = 0; r < 8; r++) rv[r] = *(const float4*)&sm.r.rows[r][k0 + kb];
#pragma unroll
      for (int e = 0; e < 4; e++) {
        const float4 w = *(const float4*)&W1[(size_t)(k0 + kb + e) * RH + hu0];
#pragma unroll
        for (int r = 0; r < 8; r++) {
          const float rx = (&rv[r].x)[e];
          acc[r][0] += rx * w.x; acc[r][1] += rx * w.y;
          acc[r][2] += rx * w.z; acc[r][3] += rx * w.w;
        }
      }
    }
#pragma unroll
    for (int r = 0; r < 8; r++)
      *(float4*)&sm.r.part[tid >> 5][r][hu0] =
          (float4){acc[r][0], acc[r][1], acc[r][2], acc[r][3]};
    __syncthreads();

    {
      const int p0 = tid * 4;
      const int r = p0 >> 7, hu = p0 & 127;
      float4 s = {0.f, 0.f, 0.f, 0.f};
#pragma unroll
      for (int sl = 0; sl < 8; sl++) {
        const float4 v = *(const float4*)&sm.r.part[sl][r][hu];
        s.x += v.x; s.y += v.y; s.z += v.z; s.w += v.w;
      }
      const float4 bv = *(const float4*)&b1[hu];
      *(float4*)&sm.r.hid[r][hu] = (float4){tanhf(s.x + bv.x), tanhf(s.y + bv.y),
                                            tanhf(s.z + bv.z), tanhf(s.w + bv.w)};
    }
    __syncthreads();

    if (tid < 128) {
      const int r = tid >> 4, bin = tid & 15;
      float a = b2[bin];
#pragma unroll
      for (int jj = 0; jj < RH; jj++) a += sm.r.hid[r][jj] * W2[jj * NB + bin];
      sm.r.logits[r][bin] = a;
    }
    __syncthreads();

    if (tid < 8) {
      const int r = tid;
      float mx = -INFINITY;
#pragma unroll
      for (int bin = 0; bin < NB; bin++) mx = fmaxf(mx, sm.r.logits[r][bin]);
      float e[NB];
      float s = 0.0f;
#pragma unroll
      for (int bin = 0; bin < NB; bin++) {
        e[bin] = expf(sm.r.logits[r][bin] - mx);
        s += e[bin];
      }
      const float inv = 1.0f / s;
      const size_t row = (size_t)(b * T_ + t0 + r) * NB;
#pragma unroll
      for (int bin = 0; bin < NB; bin++) probs[row + bin] = e[bin] * inv;
    }
  } else {  // ======== cvt: one 64-key tile of one head =====================
    const int blk = blockIdx.x - 512;  // bh*16 + kt
    const int bh = blk >> 4, kt = blk & 15;
    const float* kp = kin + (size_t)bh * (T_ * D_) + (size_t)kt * (64 * D_);
    const float* vp = vin + (size_t)bh * (T_ * D_) + (size_t)kt * (64 * D_);
    char* kh = (char*)khi + (size_t)blk * 8192;
    char* kl = (char*)klo + (size_t)blk * 8192;
    char* vh = (char*)vthi + (size_t)blk * 8192;
    char* vl = (char*)vtlo + (size_t)blk * 8192;

    // K: no transpose; write pre-swizzled hi/lo. Also stage V tile in LDS.
#pragma unroll
    for (int it = 0; it < 4; it++) {
      const int flat4 = tid + 256 * it;
      const int key = flat4 >> 4, d0 = (flat4 & 15) * 4;
      const float4 f = *(const float4*)(kp + (size_t)key * D_ + d0);
      union { unsigned short us[4]; uint2 u; } h, l;
#pragma unroll
      for (int e = 0; e < 4; e++) {
        const float x = (&f.x)[e];
        const unsigned short hh = f2bf(x);
        h.us[e] = hh; l.us[e] = f2bf(x - bf2f(hh));
      }
      const unsigned dst =
          ((unsigned)(key * 128 + d0 * 2)) ^ (((unsigned)(key & 7)) << 4);
      *(uint2*)(kh + dst) = h.u;
      *(uint2*)(kl + dst) = l.u;
      *(float4*)&sm.vt[key][d0] = f;  // overwritten below? no: vt is V only
    }
    // separate V stage (distinct loop keeps K-reg pressure low)
#pragma unroll
    for (int it = 0; it < 4; it++) {
      const int flat4 = tid + 256 * it;
      const int key = flat4 >> 4, d0 = (flat4 & 15) * 4;
      *(float4*)&sm.vt[key][d0] = *(const float4*)(vp + (size_t)key * D_ + d0);
    }
    __syncthreads();

    // V^T: thread (d = tid&63, tc = (tid>>6)*16) -> 16 keys of row d
    const int d = tid & 63, tc = (tid >> 6) * 16;
    union { unsigned short us[8]; uint4 u; } h0, h1, l0, l1;
#pragma unroll
    for (int i = 0; i < 16; i++) {
      const float x = sm.vt[tc + i][d];
      const unsigned short hh = f2bf(x);
      const unsigned short ll = f2bf(x - bf2f(hh));
      if (i < 8) { h0.us[i] = hh; l0.us[i] = ll; }
      else       { h1.us[i - 8] = hh; l1.us[i - 8] = ll; }
    }
    const unsigned sw = ((unsigned)(d & 7)) << 4;
    const unsigned vb0 = ((unsigned)(d * 128 + tc * 2)) ^ sw;
    const unsigned vb1 = ((unsigned)(d * 128 + tc * 2 + 16)) ^ sw;
    *(uint4*)(vh + vb0) = h0.u; *(uint4*)(vh + vb1) = h1.u;
    *(uint4*)(vl + vb0) = l0.u; *(uint4*)(vl + vb1) = l1.u;
  }
}

// ---------------- Stage 2: bitmask v3 (512 blocks, no LDS) -----------------
__global__ __launch_bounds__(256) void mask_v3(
    const float* __restrict__ probs, unsigned long long* __restrict__ mask) {
  const int blk = blockIdx.x;
  const int b = blk >> 7, i0 = (blk & 127) << 3;
  const int tid = threadIdx.x, w = tid >> 6;

  float4 pjv[4][4];
#pragma unroll
  for (int jc = 0; jc < 4; jc++) {
    const float4* pjp =
        (const float4*)(probs + ((size_t)(b * T_ + jc * 256 + tid)) * NB);
#pragma unroll
    for (int qq = 0; qq < 4; qq++) pjv[jc][qq] = pjp[qq];
  }

  for (int ii = 0; ii < 8; ii++) {
    const int i = i0 + ii;
    const float4* pip = (const float4*)(probs + ((size_t)(b * T_ + i)) * NB);
    const float4 p0 = pip[0], p1 = pip[1], p2 = pip[2], p3 = pip[3];
#pragma unroll
    for (int jc = 0; jc < 4; jc++) {
      const int j = jc * 256 + tid;
      float sim = p0.x * pjv[jc][0].x + p0.y * pjv[jc][0].y +
                  p0.z * pjv[jc][0].z + p0.w * pjv[jc][0].w;
      sim += p1.x * pjv[jc][1].x + p1.y * pjv[jc][1].y +
             p1.z * pjv[jc][1].z + p1.w * pjv[jc][1].w;
      sim += p2.x * pjv[jc][2].x + p2.y * pjv[jc][2].y +
             p2.z * pjv[jc][2].z + p2.w * pjv[jc][2].w;
      sim += p3.x * pjv[jc][3].x + p3.y * pjv[jc][3].y +
             p3.z * pjv[jc][3].z + p3.w * pjv[jc][3].w;
      const unsigned long long bal = __ballot((j <= i) && (sim > 0.05f));
      if ((tid & 63) == 0)
        mask[((size_t)(b * T_ + i) << 4) + jc * 4 + w] = bal;
    }
  }
}

// ---------------- fast attention: preconverted bf16 tiles ------------------
// 1D grid, qt DESCENDING (heavy blocks first). Staging = linear uint4 copy.
// QK^T 3-term split; PV 2-term (P_hi x V_hi + P_hi x V_lo).
__global__ __launch_bounds__(256, 2) void attn_bf16(
    const float* __restrict__ q,
    const unsigned short* __restrict__ khi, const unsigned short* __restrict__ klo,
    const unsigned short* __restrict__ vthi, const unsigned short* __restrict__ vtlo,
    const unsigned long long* __restrict__ mask, float* __restrict__ out) {
  __shared__ unsigned short Kh[64 * 64], Kl[64 * 64];    // [key][d]  swz
  __shared__ unsigned short Vth[64 * 64], Vtl[64 * 64];  // [d][key]  swz
  __shared__ unsigned short Phs[4][1024];                // per-wave P_hi

  const int bid = blockIdx.x;
  const int qt = 15 - (bid >> 6);     // heavy first
  const int bh = bid & 63;
  const int b = bh >> 4;
  const int tid = threadIdx.x, w = tid >> 6, lane = tid & 63;
  const int lr = lane & 15, g = lane >> 4;
  const size_t base = (size_t)bh * (T_ * D_);
  const int qrow_g = qt * 64 + w * 16 + lr;
  const unsigned swz = ((unsigned)(lr & 7)) << 4;

  // Q fragments (pre-scaled by 0.125, split hi/lo)
  s16x8 qfh[2], qfl[2];
  {
    const float* qp = q + base + (size_t)qrow_g * D_;
#pragma unroll
    for (int ks = 0; ks < 2; ks++) {
      union { unsigned short us[8]; s16x8 v; } h, l;
#pragma unroll
      for (int e2 = 0; e2 < 2; e2++) {
        const float4 f = *(const float4*)(qp + 32 * ks + 8 * g + 4 * e2);
#pragma unroll
        for (int e = 0; e < 4; e++) {
          const float x = (&f.x)[e] * 0.125f;
          const unsigned short hh = f2bf(x);
          h.us[4 * e2 + e] = hh;
          l.us[4 * e2 + e] = f2bf(x - bf2f(hh));
        }
      }
      qfh[ks] = h.v; qfl[ks] = l.v;
    }
  }

  f32x4 Oacc[4];
#pragma unroll
  for (int n = 0; n < 4; n++) Oacc[n] = (f32x4){0.f, 0.f, 0.f, 0.f};
  float mrun = -INFINITY, lrun = 0.f;

  const unsigned long long* mrow = mask + ((size_t)(b * T_ + qrow_g) << 4);
  const uint4* gkh = (const uint4*)khi + (size_t)bh * (16 * 512);
  const uint4* gkl = (const uint4*)klo + (size_t)bh * (16 * 512);
  const uint4* gvh = (const uint4*)vthi + (size_t)bh * (16 * 512);
  const uint4* gvl = (const uint4*)vtlo + (size_t)bh * (16 * 512);

  uint4 st[8], st2[8];
  {
    st[0] = gkh[tid];       st[1] = gkh[tid + 256];
    st[2] = gkl[tid];       st[3] = gkl[tid + 256];
    st[4] = gvh[tid];       st[5] = gvh[tid + 256];
    st[6] = gvl[tid];       st[7] = gvl[tid + 256];
  }
  unsigned long long mw = mrow[0];

  for (int kt = 0; kt <= qt; kt++) {
    __syncthreads();  // previous tile's LDS reads done
    ((uint4*)Kh)[tid] = st[0];  ((uint4*)Kh)[tid + 256] = st[1];
    ((uint4*)Kl)[tid] = st[2];  ((uint4*)Kl)[tid + 256] = st[3];
    ((uint4*)Vth)[tid] = st[4]; ((uint4*)Vth)[tid + 256] = st[5];
    ((uint4*)Vtl)[tid] = st[6]; ((uint4*)Vtl)[tid + 256] = st[7];
    __syncthreads();  // staged tile visible

    const int ktn = (kt < qt) ? kt + 1 : qt;
    {
      const size_t toff = (size_t)ktn * 512;
      st2[0] = gkh[toff + tid];       st2[1] = gkh[toff + tid + 256];
      st2[2] = gkl[toff + tid];       st2[3] = gkl[toff + tid + 256];
      st2[4] = gvh[toff + tid];       st2[5] = gvh[toff + tid + 256];
      st2[6] = gvl[toff + tid];       st2[7] = gvl[toff + tid + 256];
    }
    const unsigned long long mwn = mrow[ktn];

    if (__any(mw != 0ull)) {
      // ---- QK^T (swapped, 3-term): S4[m][r] = S[key=16m+4g+r][qrow=lr]
      f32x4 S4[4];
#pragma unroll
      for (int m = 0; m < 4; m++) {
        f32x4 acc = (f32x4){0.f, 0.f, 0.f, 0.f};
#pragma unroll
        for (int ks = 0; ks < 2; ks++) {
          const unsigned byte =
              ((unsigned)((16 * m + lr) * 128 + 64 * ks + 16 * g)) ^ swz;
          const s16x8 kfh = *(const s16x8*)((const char*)Kh + byte);
          const s16x8 kfl = *(const s16x8*)((const char*)Kl + byte);
          acc = __builtin_amdgcn_mfma_f32_16x16x32_bf16(kfh, qfh[ks], acc, 0, 0, 0);
          acc = __builtin_amdgcn_mfma_f32_16x16x32_bf16(kfh, qfl[ks], acc, 0, 0, 0);
          acc = __builtin_amdgcn_mfma_f32_16x16x32_bf16(kfl, qfh[ks], acc, 0, 0, 0);
        }
        S4[m] = acc;
      }

      // ---- mask + online softmax (row = lr) ----
      float sv[16]; unsigned okb = 0; float tmax = -INFINITY;
#pragma unroll
      for (int jj = 0; jj < 16; jj++) {
        const int bit = 16 * (jj >> 2) + 4 * g + (jj & 3);
        const bool ok = (mw >> bit) & 1ull;
        okb |= ((unsigned)ok) << jj;
        const float s = ok ? S4[jj >> 2][jj & 3] : -INFINITY;
        sv[jj] = s; tmax = fmaxf(tmax, s);
      }
      tmax = fmaxf(tmax, __shfl_xor(tmax, 16));
      tmax = fmaxf(tmax, __shfl_xor(tmax, 32));
      if (__any(tmax > mrun + 8.0f)) {  // T13 defer-max
        const float mnew = fmaxf(mrun, tmax);
        const float corr = (mnew == -INFINITY) ? 1.0f : __expf(mrun - mnew);
        lrun *= corr; mrun = mnew;
        float cr[4];
#pragma unroll
        for (int r = 0; r < 4; r++) cr[r] = __shfl(corr, 4 * g + r);
#pragma unroll
        for (int n = 0; n < 4; n++)
#pragma unroll
          for (int r = 0; r < 4; r++) Oacc[n][r] *= cr[r];
      }
      float pj[16]; float lsum = 0.f;
#pragma unroll
      for (int jj = 0; jj < 16; jj++) {
        const float e = __expf(sv[jj] - mrun);
        const float pv = ((okb >> jj) & 1u) ? e : 0.f;
        pj[jj] = pv; lsum += pv;
      }
      lsum += __shfl_xor(lsum, 16);
      lsum += __shfl_xor(lsum, 32);
      lrun += lsum;

      // ---- P_hi -> per-wave LDS [qrow][key] ----
#pragma unroll
      for (int m = 0; m < 4; m++) {
        union { unsigned short us[4]; uint2 d; } h;
#pragma unroll
        for (int r = 0; r < 4; r++) h.us[r] = f2bf(pj[4 * m + r]);
        const unsigned byte =
            ((unsigned)(lr * 128 + (16 * m + 4 * g) * 2)) ^ swz;
        *(uint2*)((char*)Phs + 2048 * w + byte) = h.d;
      }
      asm volatile("s_waitcnt lgkmcnt(0)" ::: "memory");
      __builtin_amdgcn_sched_barrier(0);

      // ---- PV (2-term): O += P_hi . (V_hi + V_lo) ----
#pragma unroll
      for (int ks = 0; ks < 2; ks++) {
        const unsigned pb = ((unsigned)(lr * 128 + 64 * ks + 16 * g)) ^ swz;
        const s16x8 pfh = *(const s16x8*)((const char*)Phs + 2048 * w + pb);
#pragma unroll
        for (int n = 0; n < 4; n++) {
          const unsigned vb =
              ((unsigned)((16 * n + lr) * 128 + 64 * ks + 16 * g)) ^ swz;
          const s16x8 vfh = *(const s16x8*)((const char*)Vth + vb);
          const s16x8 vfl = *(const s16x8*)((const char*)Vtl + vb);
          Oacc[n] = __builtin_amdgcn_mfma_f32_16x16x32_bf16(pfh, vfh, Oacc[n], 0, 0, 0);
          Oacc[n] = __builtin_amdgcn_mfma_f32_16x16x32_bf16(pfh, vfl, Oacc[n], 0, 0, 0);
        }
      }
    }  // any mask bit

#pragma unroll
    for (int i = 0; i < 8; i++) st[i] = st2[i];
    mw = mwn;
  }

  const float linv = 1.0f / lrun;
  float lr4[4];
#pragma unroll
  for (int r = 0; r < 4; r++) lr4[r] = __shfl(linv, 4 * g + r);
  const int orow0 = qt * 64 + w * 16;
  float* op = out + base;
#pragma unroll
  for (int n = 0; n < 4; n++)
#pragma unroll
    for (int r = 0; r < 4; r++)
      op[(size_t)(orow0 + 4 * g + r) * D_ + 16 * n + lr] = Oacc[n][r] * lr4[r];
}

// ---------------- fallback attention (round-9 kernel, verbatim math) -------
__global__ __launch_bounds__(256, 2) void attn_mfma(
    const float* __restrict__ q, const float* __restrict__ k,
    const float* __restrict__ v, const unsigned long long* __restrict__ mask,
    float* __restrict__ out) {
  __shared__ unsigned short Kh[64 * 64], Kl[64 * 64];
  __shared__ unsigned short Vth[64 * 64], Vtl[64 * 64];
  __shared__ unsigned short Phs[4][1024], Pls[4][1024];

  const int bh = blockIdx.x, qt = blockIdx.y;
  const int b = bh >> 4;
  const int tid = threadIdx.x, w = tid >> 6, lane = tid & 63;
  const int lr = lane & 15;
  const int g = lane >> 4;
  const size_t base = (size_t)bh * (T_ * D_);
  const int qrow_g = qt * 64 + w * 16 + lr;
  const unsigned swz = ((unsigned)(lr & 7)) << 4;

  s16x8 qfh[2], qfl[2];
  {
    const float* qp = q + base + (size_t)qrow_g * D_;
#pragma unroll
    for (int ks = 0; ks < 2; ks++) {
      union { unsigned short us[8]; s16x8 v; } h, l;
#pragma unroll
      for (int e2 = 0; e2 < 2; e2++) {
        const float4 f = *(const float4*)(qp + 32 * ks + 8 * g + 4 * e2);
#pragma unroll
        for (int e = 0; e < 4; e++) {
          const float x = (&f.x)[e] * 0.125f;
          const unsigned short hh = f2bf(x);
          h.us[4 * e2 + e] = hh;
          l.us[4 * e2 + e] = f2bf(x - bf2f(hh));
        }
      }
      qfh[ks] = h.v; qfl[ks] = l.v;
    }
  }

  f32x4 Oacc[4];
#pragma unroll
  for (int n = 0; n < 4; n++) Oacc[n] = (f32x4){0.f, 0.f, 0.f, 0.f};
  float mrun = -INFINITY, lrun = 0.f;

  const unsigned long long* mrow = mask + ((size_t)(b * T_ + qrow_g) << 4);
  const int dv = tid & 63, k0v = (tid >> 6) * 16;

  float Kst[16], Vst[16], Kst2[16], Vst2[16];
  {
    const float4* kp4 = (const float4*)(k + base);
    const float* vp = v + base;
#pragma unroll
    for (int i = 0; i < 4; i++) {
      const float4 f = kp4[tid + 256 * i];
      Kst[4 * i + 0] = f.x; Kst[4 * i + 1] = f.y;
      Kst[4 * i + 2] = f.z; Kst[4 * i + 3] = f.w;
    }
#pragma unroll
    for (int j = 0; j < 16; j++) Vst[j] = vp[(size_t)(k0v + j) * D_ + dv];
  }
  unsigned long long mw = mrow[0];

  for (int kt = 0; kt <= qt; kt++) {
    __syncthreads();
#pragma unroll
    for (int i = 0; i < 4; i++) {
      const int flat4 = tid + 256 * i, key = flat4 >> 4, dq = flat4 & 15;
      union { unsigned short us[4]; uint2 d; } h, l;
#pragma unroll
      for (int e = 0; e < 4; e++) {
        const float x = Kst[4 * i + e];
        const unsigned short hh = f2bf(x);
        h.us[e] = hh; l.us[e] = f2bf(x - bf2f(hh));
      }
      const unsigned byte = (unsigned)(key * 128 + dq * 8) ^ (((unsigned)(key & 7)) << 4);
      *(uint2*)((char*)Kh + byte) = h.d;
      *(uint2*)((char*)Kl + byte) = l.d;
    }
#pragma unroll
    for (int i = 0; i < 2; i++) {
      union { unsigned short us[8]; uint4 q; } h, l;
#pragma unroll
      for (int j = 0; j < 8; j++) {
        const float x = Vst[8 * i + j];
        const unsigned short hh = f2bf(x);
        h.us[j] = hh; l.us[j] = f2bf(x - bf2f(hh));
      }
      const unsigned byte =
          (unsigned)(dv * 128 + (k0v + 8 * i) * 2) ^ (((unsigned)(dv & 7)) << 4);
      *(uint4*)((char*)Vth + byte) = h.q;
      *(uint4*)((char*)Vtl + byte) = l.q;
    }
    __syncthreads();

    const int ktn = (kt < qt) ? kt + 1 : qt;
    {
      const float4* kp4 = (const float4*)(k + base + (size_t)(ktn * 64) * D_);
      const float* vp = v + base + (size_t)(ktn * 64) * D_;
#pragma unroll
      for (int i = 0; i < 4; i++) {
        const float4 f = kp4[tid + 256 * i];
        Kst2[4 * i + 0] = f.x; Kst2[4 * i + 1] = f.y;
        Kst2[4 * i + 2] = f.z; Kst2[4 * i + 3] = f.w;
      }
#pragma unroll
      for (int j = 0; j < 16; j++) Vst2[j] = vp[(size_t)(k0v + j) * D_ + dv];
    }
    const unsigned long long mwn = mrow[ktn];

    if (__any(mw != 0ull)) {
      f32x4 S4[4];
#pragma unroll
      for (int m = 0; m < 4; m++) {
        f32x4 acc = (f32x4){0.f, 0.f, 0.f, 0.f};
#pragma unroll
        for (int ks = 0; ks < 2; ks++) {
          const unsigned byte =
              ((unsigned)((16 * m + lr) * 128 + 64 * ks + 16 * g)) ^ swz;
          const s16x8 kfh = *(const s16x8*)((const char*)Kh + byte);
          const s16x8 kfl = *(const s16x8*)((const char*)Kl + byte);
          acc = __builtin_amdgcn_mfma_f32_16x16x32_bf16(kfh, qfh[ks], acc, 0, 0, 0);
          acc = __builtin_amdgcn_mfma_f32_16x16x32_bf16(kfh, qfl[ks], acc, 0, 0, 0);
          acc = __builtin_amdgcn_mfma_f32_16x16x32_bf16(kfl, qfh[ks], acc, 0, 0, 0);
        }
        S4[m] = acc;
      }

      float sv[16]; unsigned okb = 0; float tmax = -INFINITY;
#pragma unroll
      for (int jj = 0; jj < 16; jj++) {
        const int bit = 16 * (jj >> 2) + 4 * g + (jj & 3);
        const bool ok = (mw >> bit) & 1ull;
        okb |= ((unsigned)ok) << jj;
        const float s = ok ? S4[jj >> 2][jj & 3] : -INFINITY;
        sv[jj] = s; tmax = fmaxf(tmax, s);
      }
      tmax = fmaxf(tmax, __shfl_xor(tmax, 16));
      tmax = fmaxf(tmax, __shfl_xor(tmax, 32));
      if (__any(tmax > mrun + 8.0f)) {
        const float mnew = fmaxf(mrun, tmax);
        const float corr = (mnew == -INFINITY) ? 1.0f : __expf(mrun - mnew);
        lrun *= corr; mrun = mnew;
        float cr[4];
#pragma unroll
        for (int r = 0; r < 4; r++) cr[r] = __shfl(corr, 4 * g + r);
#pragma unroll
        for (int n = 0; n < 4; n++)
#pragma unroll
          for (int r = 0; r < 4; r++) Oacc[n][r] *= cr[r];
      }
      float pj[16]; float lsum = 0.f;
#pragma unroll
      for (int jj = 0; jj < 16; jj++) {
        const float e = __expf(sv[jj] - mrun);
        const float pv = ((okb >> jj) & 1u) ? e : 0.f;
        pj[jj] = pv; lsum += pv;
      }
      lsum += __shfl_xor(lsum, 16);
      lsum += __shfl_xor(lsum, 32);
      lrun += lsum;

#pragma unroll
      for (int m = 0; m < 4; m++) {
        union { unsigned short us[4]; uint2 d; } h, l;
#pragma unroll
        for (int r = 0; r < 4; r++) {
          const float pv = pj[4 * m + r];
          const unsigned short hh = f2bf(pv);
          h.us[r] = hh; l.us[r] = f2bf(pv - bf2f(hh));
        }
        const unsigned byte =
            ((unsigned)(lr * 128 + (16 * m + 4 * g) * 2)) ^ swz;
        *(uint2*)((char*)Phs + 2048 * w + byte) = h.d;
        *(uint2*)((char*)Pls + 2048 * w + byte) = l.d;
      }
      asm volatile("s_waitcnt lgkmcnt(0)" ::: "memory");
      __builtin_amdgcn_sched_barrier(0);

#pragma unroll
      for (int ks = 0; ks < 2; ks++) {
        const unsigned pb = ((unsigned)(lr * 128 + 64 * ks + 16 * g)) ^ swz;
        const s16x8 pfh = *(const s16x8*)((const char*)Phs + 2048 * w + pb);
        const s16x8 pfl = *(const s16x8*)((const char*)Pls + 2048 * w + pb);
#pragma unroll
        for (int n = 0; n < 4; n++) {
          const unsigned vb =
              ((unsigned)((16 * n + lr) * 128 + 64 * ks + 16 * g)) ^ swz;
          const s16x8 vfh = *(const s16x8*)((const char*)Vth + vb);
          const s16x8 vfl = *(const s16x8*)((const char*)Vtl + vb);
          Oacc[n] = __builtin_amdgcn_mfma_f32_16x16x32_bf16(pfh, vfh, Oacc[n], 0, 0, 0);
          Oacc[n] = __builtin_amdgcn_mfma_f32_16x16x32_bf16(pfh, vfl, Oacc[n], 0, 0, 0);
          Oacc[n] = __builtin_amdgcn_mfma_f32_16x16x32_bf16(pfl, vfh, Oacc[n], 0, 0, 0);
        }
      }
    }

#pragma unroll
    for (int i = 0; i < 16; i++) { Kst[i] = Kst2[i]; Vst[i] = Vst2[i]; }
    mw = mwn;
  }

  const float linv = 1.0f / lrun;
  float lr4[4];
#pragma unroll
  for (int r = 0; r < 4; r++) lr4[r] = __shfl(linv, 4 * g + r);
  const int orow0 = qt * 64 + w * 16;
  float* op = out + base;
#pragma unroll
  for (int n = 0; n < 4; n++)
#pragma unroll
    for (int r = 0; r < 4; r++)
      op[(size_t)(orow0 + 4 * g + r) * D_ + 16 * n + lr] = Oacc[n][r] * lr4[r];
}

extern "C" void kernel_launch(void* const* d_in, const int* in_sizes, int n_in,
                              void* d_out, int out_size, void* d_ws, size_t ws_size,
                              hipStream_t stream) {
  const float* q  = (const float*)d_in[0];
  const float* k  = (const float*)d_in[1];
  const float* v  = (const float*)d_in[2];
  const float* W1 = (const float*)d_in[3];
  const float* b1 = (const float*)d_in[4];
  const float* W2 = (const float*)d_in[5];
  const float* b2 = (const float*)d_in[6];
  float* out = (float*)d_out;

  // ws: probs 256KB | mask 512KB | Khi,Klo,VThi,VTlo 8MB each (fast path)
  float* probs = (float*)d_ws;
  unsigned long long* mask = (unsigned long long*)((char*)d_ws + 262144);
  const size_t NEED = 786432ull + 4ull * 8388608ull;

  if (ws_size >= NEED) {
    unsigned short* khi  = (unsigned short*)((char*)d_ws + 786432);
    unsigned short* klo  = (unsigned short*)((char*)d_ws + 786432 + 8388608ull);
    unsigned short* vthi = (unsigned short*)((char*)d_ws + 786432 + 16777216ull);
    unsigned short* vtlo = (unsigned short*)((char*)d_ws + 786432 + 25165824ull);
    prep_kernel<<<1536, 256, 0, stream>>>(k, v, W1, b1, W2, b2, probs,
                                          khi, klo, vthi, vtlo);
    mask_v3<<<512, 256, 0, stream>>>(probs, mask);
    attn_bf16<<<1024, 256, 0, stream>>>(q, khi, klo, vthi, vtlo, mask, out);
  } else {
    prep_kernel<<<512, 256, 0, stream>>>(k, v, W1, b1, W2, b2, probs,
                                         nullptr, nullptr, nullptr, nullptr);
    mask_v3<<<512, 256, 0, stream>>>(probs, mask);
    attn_mfma<<<dim3(B_ * H_, T_ / 64), 256, 0, stream>>>(q, k, v, mask, out);
  }
}

// Round 11
// 167.608 us; speedup vs baseline: 1.4302x; 1.4302x over previous
//
#include <hip/hip_runtime.h>
#include <hip/hip_bf16.h>

// SubQAttention: B=4, H=16, T=1024, D=64, N_BINS=16, ROUTER_HIDDEN=128
// Fast path (ws >= 33.3MB):
//   prep_kernel : blocks 0-511 router -> probs; blocks 512-1535 convert
//                 K -> (Khi,Klo) [key][d] and V^T -> (VThi,VTlo) [d][key],
//                 bf16 hi/lo split, PRE-SWIZZLED per 64-tile (byte ^= (row&7)<<4)
//   mask_v3     : bucket&causal bitmask [B*T,16] u64
//   attn_bf16   : MFMA flash attention; staging = global_load_lds (width 16,
//                 ZERO staging VGPRs - round 10's st[]/st2[] spilled 313MB to
//                 scratch), double-buffered LDS, counted vmcnt(8) pipeline.
// Fallback (small ws): round-9 attn_mfma (in-kernel cvt, 3-term PV).

#define B_ 4
#define H_ 16
#define T_ 1024
#define D_ 64
#define NB 16
#define RH 128

typedef __attribute__((ext_vector_type(8))) short s16x8;
typedef __attribute__((ext_vector_type(4))) float f32x4;

__device__ __forceinline__ unsigned short f2bf(float x) {  // HW RNE cast
  union { __hip_bfloat16 b; unsigned short u; } c;
  c.b = __hip_bfloat16(x);
  return c.u;
}
__device__ __forceinline__ float bf2f(unsigned short h) {
  return __uint_as_float(((unsigned)h) << 16);
}
__device__ __forceinline__ void gload16(const void* g, void* l) {
  // direct global->LDS DMA; LDS dst = wave-uniform base + lane*16
  __builtin_amdgcn_global_load_lds(
      (const __attribute__((address_space(1))) unsigned int*)g,
      (__attribute__((address_space(3))) unsigned int*)l, 16, 0, 0);
}

// ---------------- prep: router (blocks 0-511) + K/V cvt (512-1535) ---------
__global__ __launch_bounds__(256) void prep_kernel(
    const float* __restrict__ kin, const float* __restrict__ vin,
    const float* __restrict__ W1, const float* __restrict__ b1,
    const float* __restrict__ W2, const float* __restrict__ b2,
    float* __restrict__ probs,
    unsigned short* __restrict__ khi, unsigned short* __restrict__ klo,
    unsigned short* __restrict__ vthi, unsigned short* __restrict__ vtlo) {
  __shared__ union {
    struct {
      float rows[8][1024];
      float part[8][8][RH];
      float hid[8][RH + 4];
      float logits[8][NB];
    } r;
    float vt[64][68];  // padded transpose staging
  } sm;
  const int tid = threadIdx.x;

  if (blockIdx.x < 512) {  // ======== router (identical math to round 9) ====
    const int bb = blockIdx.x;
    const int b = bb >> 7;
    const int t0 = (bb & 127) << 3;

#pragma unroll
    for (int s = 0; s < 8; s++) {
      const int idx4 = tid + 256 * s;
      const int r = idx4 >> 8, i = (idx4 & 255) * 4;
      const int h = i >> 6, d = i & 63;
      *(float4*)&sm.r.rows[r][i] =
          *(const float4*)&kin[(((size_t)(b * H_) + h) * T_ + (t0 + r)) * D_ + d];
    }
    __syncthreads();

    const int hu0 = (tid & 31) << 2;
    const int k0 = (tid >> 5) << 7;
    float acc[8][4];
#pragma unroll
    for (int r = 0; r < 8; r++)
#pragma unroll
      for (int c = 0; c < 4; c++) acc[r][c] = 0.0f;

    for (int kb = 0; kb < 128; kb += 4) {
      float4 rv[8];
#pragma unroll
      for (int r = 0; r < 8; r++) rv[r] = *(const float4*)&sm.r.rows[r][k0 + kb];
#pragma unroll
      for (int e = 0; e < 4; e++) {
        const float4 w = *(const float4*)&W1[(size_t)(k0 + kb + e) * RH + hu0];
#pragma unroll
        for (int r = 0; r < 8; r++) {
          const float rx = (&rv[r].x)[e];
          acc[r][0] += rx * w.x; acc[r][1] += rx * w.y;
          acc[r][2] += rx * w.z; acc[r][3] += rx * w.w;
        }
      }
    }
#pragma unroll
    for (int r = 0; r < 8; r++)
      *(float4*)&sm.r.part[tid >> 5][r][hu0] =
          (float4){acc[r][0], acc[r][1], acc[r][2], acc[r][3]};
    __syncthreads();

    {
      const int p0 = tid * 4;
      const int r = p0 >> 7, hu = p0 & 127;
      float4 s = {0.f, 0.f, 0.f, 0.f};
#pragma unroll
      for (int sl = 0; sl < 8; sl++) {
        const float4 v = *(const float4*)&sm.r.part[sl][r][hu];
        s.x += v.x; s.y += v.y; s.z += v.z; s.w += v.w;
      }
      const float4 bv = *(const float4*)&b1[hu];
      *(float4*)&sm.r.hid[r][hu] = (float4){tanhf(s.x + bv.x), tanhf(s.y + bv.y),
                                            tanhf(s.z + bv.z), tanhf(s.w + bv.w)};
    }
    __syncthreads();

    if (tid < 128) {
      const int r = tid >> 4, bin = tid & 15;
      float a = b2[bin];
#pragma unroll
      for (int jj = 0; jj < RH; jj++) a += sm.r.hid[r][jj] * W2[jj * NB + bin];
      sm.r.logits[r][bin] = a;
    }
    __syncthreads();

    if (tid < 8) {
      const int r = tid;
      float mx = -INFINITY;
#pragma unroll
      for (int bin = 0; bin < NB; bin++) mx = fmaxf(mx, sm.r.logits[r][bin]);
      float e[NB];
      float s = 0.0f;
#pragma unroll
      for (int bin = 0; bin < NB; bin++) {
        e[bin] = expf(sm.r.logits[r][bin] - mx);
        s += e[bin];
      }
      const float inv = 1.0f / s;
      const size_t row = (size_t)(b * T_ + t0 + r) * NB;
#pragma unroll
      for (int bin = 0; bin < NB; bin++) probs[row + bin] = e[bin] * inv;
    }
  } else {  // ======== cvt: one 64-key tile of one head =====================
    const int blk = blockIdx.x - 512;  // bh*16 + kt
    const int bh = blk >> 4, kt = blk & 15;
    const float* kp = kin + (size_t)bh * (T_ * D_) + (size_t)kt * (64 * D_);
    const float* vp = vin + (size_t)bh * (T_ * D_) + (size_t)kt * (64 * D_);
    char* kh = (char*)khi + (size_t)blk * 8192;
    char* kl = (char*)klo + (size_t)blk * 8192;
    char* vh = (char*)vthi + (size_t)blk * 8192;
    char* vl = (char*)vtlo + (size_t)blk * 8192;

    // K: no transpose; write pre-swizzled hi/lo.
#pragma unroll
    for (int it = 0; it < 4; it++) {
      const int flat4 = tid + 256 * it;
      const int key = flat4 >> 4, d0 = (flat4 & 15) * 4;
      const float4 f = *(const float4*)(kp + (size_t)key * D_ + d0);
      union { unsigned short us[4]; uint2 u; } h, l;
#pragma unroll
      for (int e = 0; e < 4; e++) {
        const float x = (&f.x)[e];
        const unsigned short hh = f2bf(x);
        h.us[e] = hh; l.us[e] = f2bf(x - bf2f(hh));
      }
      const unsigned dst =
          ((unsigned)(key * 128 + d0 * 2)) ^ (((unsigned)(key & 7)) << 4);
      *(uint2*)(kh + dst) = h.u;
      *(uint2*)(kl + dst) = l.u;
    }
    // V stage to LDS for transpose
#pragma unroll
    for (int it = 0; it < 4; it++) {
      const int flat4 = tid + 256 * it;
      const int key = flat4 >> 4, d0 = (flat4 & 15) * 4;
      *(float4*)&sm.vt[key][d0] = *(const float4*)(vp + (size_t)key * D_ + d0);
    }
    __syncthreads();

    // V^T: thread (d = tid&63, tc = (tid>>6)*16) -> 16 keys of row d
    const int d = tid & 63, tc = (tid >> 6) * 16;
    union { unsigned short us[8]; uint4 u; } h0, h1, l0, l1;
#pragma unroll
    for (int i = 0; i < 16; i++) {
      const float x = sm.vt[tc + i][d];
      const unsigned short hh = f2bf(x);
      const unsigned short ll = f2bf(x - bf2f(hh));
      if (i < 8) { h0.us[i] = hh; l0.us[i] = ll; }
      else       { h1.us[i - 8] = hh; l1.us[i - 8] = ll; }
    }
    const unsigned sw = ((unsigned)(d & 7)) << 4;
    const unsigned vb0 = ((unsigned)(d * 128 + tc * 2)) ^ sw;
    const unsigned vb1 = ((unsigned)(d * 128 + tc * 2 + 16)) ^ sw;
    *(uint4*)(vh + vb0) = h0.u; *(uint4*)(vh + vb1) = h1.u;
    *(uint4*)(vl + vb0) = l0.u; *(uint4*)(vl + vb1) = l1.u;
  }
}

// ---------------- Stage 2: bitmask v3 (512 blocks, no LDS) -----------------
__global__ __launch_bounds__(256) void mask_v3(
    const float* __restrict__ probs, unsigned long long* __restrict__ mask) {
  const int blk = blockIdx.x;
  const int b = blk >> 7, i0 = (blk & 127) << 3;
  const int tid = threadIdx.x, w = tid >> 6;

  float4 pjv[4][4];
#pragma unroll
  for (int jc = 0; jc < 4; jc++) {
    const float4* pjp =
        (const float4*)(probs + ((size_t)(b * T_ + jc * 256 + tid)) * NB);
#pragma unroll
    for (int qq = 0; qq < 4; qq++) pjv[jc][qq] = pjp[qq];
  }

  for (int ii = 0; ii < 8; ii++) {
    const int i = i0 + ii;
    const float4* pip = (const float4*)(probs + ((size_t)(b * T_ + i)) * NB);
    const float4 p0 = pip[0], p1 = pip[1], p2 = pip[2], p3 = pip[3];
#pragma unroll
    for (int jc = 0; jc < 4; jc++) {
      const int j = jc * 256 + tid;
      float sim = p0.x * pjv[jc][0].x + p0.y * pjv[jc][0].y +
                  p0.z * pjv[jc][0].z + p0.w * pjv[jc][0].w;
      sim += p1.x * pjv[jc][1].x + p1.y * pjv[jc][1].y +
             p1.z * pjv[jc][1].z + p1.w * pjv[jc][1].w;
      sim += p2.x * pjv[jc][2].x + p2.y * pjv[jc][2].y +
             p2.z * pjv[jc][2].z + p2.w * pjv[jc][2].w;
      sim += p3.x * pjv[jc][3].x + p3.y * pjv[jc][3].y +
             p3.z * pjv[jc][3].z + p3.w * pjv[jc][3].w;
      const unsigned long long bal = __ballot((j <= i) && (sim > 0.05f));
      if ((tid & 63) == 0)
        mask[((size_t)(b * T_ + i) << 4) + jc * 4 + w] = bal;
    }
  }
}

// ---------------- fast attention: gload_lds + double-buffer ---------------
// 1D grid, qt DESCENDING. Staging via global_load_lds width=16 (no VGPRs),
// counted vmcnt(8) keeps next tile's 8 loads in flight across barriers.
// QK^T 3-term split; PV 2-term (P_hi x V_hi + P_hi x V_lo).
__global__ __launch_bounds__(256, 2) void attn_bf16(
    const float* __restrict__ q,
    const unsigned short* __restrict__ khi, const unsigned short* __restrict__ klo,
    const unsigned short* __restrict__ vthi, const unsigned short* __restrict__ vtlo,
    const unsigned long long* __restrict__ mask, float* __restrict__ out) {
  __shared__ uint4 KV[2][4][512];          // [dbuf][Kh,Kl,Vh,Vl][8KB] = 64KB
  __shared__ unsigned short Phs[4][1024];  // per-wave P_hi, 8KB

  const int bid = blockIdx.x;
  const int qt = 15 - (bid >> 6);     // heavy first
  const int bh = bid & 63;
  const int b = bh >> 4;
  const int tid = threadIdx.x, w = tid >> 6, lane = tid & 63;
  const int lr = lane & 15, g = lane >> 4;
  const size_t base = (size_t)bh * (T_ * D_);
  const int qrow_g = qt * 64 + w * 16 + lr;
  const unsigned swz = ((unsigned)(lr & 7)) << 4;

  const char* gkh = (const char*)khi + (size_t)bh * (16 * 8192);
  const char* gkl = (const char*)klo + (size_t)bh * (16 * 8192);
  const char* gvh = (const char*)vthi + (size_t)bh * (16 * 8192);
  const char* gvl = (const char*)vtlo + (size_t)bh * (16 * 8192);

  // Q fragments (pre-scaled by 0.125, split hi/lo)
  s16x8 qfh[2], qfl[2];
  {
    const float* qp = q + base + (size_t)qrow_g * D_;
#pragma unroll
    for (int ks = 0; ks < 2; ks++) {
      union { unsigned short us[8]; s16x8 v; } h, l;
#pragma unroll
      for (int e2 = 0; e2 < 2; e2++) {
        const float4 f = *(const float4*)(qp + 32 * ks + 8 * g + 4 * e2);
#pragma unroll
        for (int e = 0; e < 4; e++) {
          const float x = (&f.x)[e] * 0.125f;
          const unsigned short hh = f2bf(x);
          h.us[4 * e2 + e] = hh;
          l.us[4 * e2 + e] = f2bf(x - bf2f(hh));
        }
      }
      qfh[ks] = h.v; qfl[ks] = l.v;
    }
  }

  f32x4 Oacc[4];
#pragma unroll
  for (int n = 0; n < 4; n++) Oacc[n] = (f32x4){0.f, 0.f, 0.f, 0.f};
  float mrun = -INFINITY, lrun = 0.f;

  const unsigned long long* mrow = mask + ((size_t)(b * T_ + qrow_g) << 4);

  // STAGE(bufi, kt): 8 gload_lds per wave; wave w fills its 2KB quarter of
  // each of the 4 arrays. LDS dst wave-uniform; global src per-lane (+lane*16).
#define STAGE(bufi, kt)                                                      \
  do {                                                                       \
    const unsigned lds_q = (unsigned)(w * 2048);                             \
    const size_t g_q = (size_t)(kt) * 8192 + lds_q + (unsigned)(lane * 16);  \
    _Pragma("unroll")                                                        \
    for (int i2 = 0; i2 < 2; i2++) {                                         \
      gload16(gkh + g_q + i2 * 1024, (char*)&KV[bufi][0][0] + lds_q + i2 * 1024); \
      gload16(gkl + g_q + i2 * 1024, (char*)&KV[bufi][1][0] + lds_q + i2 * 1024); \
      gload16(gvh + g_q + i2 * 1024, (char*)&KV[bufi][2][0] + lds_q + i2 * 1024); \
      gload16(gvl + g_q + i2 * 1024, (char*)&KV[bufi][3][0] + lds_q + i2 * 1024); \
    }                                                                        \
  } while (0)

  STAGE(0, 0);
  unsigned long long mw = mrow[0];

  for (int kt = 0; kt <= qt; kt++) {
    const int cur = kt & 1;
    unsigned long long mwn = 0ull;
    if (kt < qt) {
      mwn = mrow[kt + 1];
      STAGE(cur ^ 1, kt + 1);
      // oldest-first retirement: waits current tile's 8 (+mask) loads,
      // leaves the 8 next-tile loads in flight across the barrier.
      asm volatile("s_waitcnt vmcnt(8)" ::: "memory");
    } else {
      asm volatile("s_waitcnt vmcnt(0)" ::: "memory");
    }
    __builtin_amdgcn_sched_barrier(0);
    __builtin_amdgcn_s_barrier();   // all waves' current-tile loads landed

    if (__any(mw != 0ull)) {
      const char* Khb = (const char*)&KV[cur][0][0];
      const char* Klb = (const char*)&KV[cur][1][0];
      const char* Vhb = (const char*)&KV[cur][2][0];
      const char* Vlb = (const char*)&KV[cur][3][0];

      // ---- QK^T (swapped, 3-term): S4[m][r] = S[key=16m+4g+r][qrow=lr]
      f32x4 S4[4];
#pragma unroll
      for (int m = 0; m < 4; m++) {
        f32x4 acc = (f32x4){0.f, 0.f, 0.f, 0.f};
#pragma unroll
        for (int ks = 0; ks < 2; ks++) {
          const unsigned byte =
              ((unsigned)((16 * m + lr) * 128 + 64 * ks + 16 * g)) ^ swz;
          const s16x8 kfh = *(const s16x8*)(Khb + byte);
          const s16x8 kfl = *(const s16x8*)(Klb + byte);
          acc = __builtin_amdgcn_mfma_f32_16x16x32_bf16(kfh, qfh[ks], acc, 0, 0, 0);
          acc = __builtin_amdgcn_mfma_f32_16x16x32_bf16(kfh, qfl[ks], acc, 0, 0, 0);
          acc = __builtin_amdgcn_mfma_f32_16x16x32_bf16(kfl, qfh[ks], acc, 0, 0, 0);
        }
        S4[m] = acc;
      }

      // ---- mask + online softmax (row = lr) ----
      float sv[16]; unsigned okb = 0; float tmax = -INFINITY;
#pragma unroll
      for (int jj = 0; jj < 16; jj++) {
        const int bit = 16 * (jj >> 2) + 4 * g + (jj & 3);
        const bool ok = (mw >> bit) & 1ull;
        okb |= ((unsigned)ok) << jj;
        const float s = ok ? S4[jj >> 2][jj & 3] : -INFINITY;
        sv[jj] = s; tmax = fmaxf(tmax, s);
      }
      tmax = fmaxf(tmax, __shfl_xor(tmax, 16));
      tmax = fmaxf(tmax, __shfl_xor(tmax, 32));
      if (__any(tmax > mrun + 8.0f)) {  // T13 defer-max
        const float mnew = fmaxf(mrun, tmax);
        const float corr = (mnew == -INFINITY) ? 1.0f : __expf(mrun - mnew);
        lrun *= corr; mrun = mnew;
        float cr[4];
#pragma unroll
        for (int r = 0; r < 4; r++) cr[r] = __shfl(corr, 4 * g + r);
#pragma unroll
        for (int n = 0; n < 4; n++)
#pragma unroll
          for (int r = 0; r < 4; r++) Oacc[n][r] *= cr[r];
      }
      float pj[16]; float lsum = 0.f;
#pragma unroll
      for (int jj = 0; jj < 16; jj++) {
        const float e = __expf(sv[jj] - mrun);
        const float pv = ((okb >> jj) & 1u) ? e : 0.f;
        pj[jj] = pv; lsum += pv;
      }
      lsum += __shfl_xor(lsum, 16);
      lsum += __shfl_xor(lsum, 32);
      lrun += lsum;

      // ---- P_hi -> per-wave LDS [qrow][key] ----
#pragma unroll
      for (int m = 0; m < 4; m++) {
        union { unsigned short us[4]; uint2 d; } h;
#pragma unroll
        for (int r = 0; r < 4; r++) h.us[r] = f2bf(pj[4 * m + r]);
        const unsigned byte =
            ((unsigned)(lr * 128 + (16 * m + 4 * g) * 2)) ^ swz;
        *(uint2*)((char*)Phs + 2048 * w + byte) = h.d;
      }
      asm volatile("s_waitcnt lgkmcnt(0)" ::: "memory");
      __builtin_amdgcn_sched_barrier(0);

      // ---- PV (2-term): O += P_hi . (V_hi + V_lo) ----
#pragma unroll
      for (int ks = 0; ks < 2; ks++) {
        const unsigned pb = ((unsigned)(lr * 128 + 64 * ks + 16 * g)) ^ swz;
        const s16x8 pfh = *(const s16x8*)((const char*)Phs + 2048 * w + pb);
#pragma unroll
        for (int n = 0; n < 4; n++) {
          const unsigned vb =
              ((unsigned)((16 * n + lr) * 128 + 64 * ks + 16 * g)) ^ swz;
          const s16x8 vfh = *(const s16x8*)(Vhb + vb);
          const s16x8 vfl = *(const s16x8*)(Vlb + vb);
          Oacc[n] = __builtin_amdgcn_mfma_f32_16x16x32_bf16(pfh, vfh, Oacc[n], 0, 0, 0);
          Oacc[n] = __builtin_amdgcn_mfma_f32_16x16x32_bf16(pfh, vfl, Oacc[n], 0, 0, 0);
        }
      }
    }  // any mask bit

    __builtin_amdgcn_s_barrier();   // protect buf[cur] before next STAGE
    mw = mwn;
  }
#undef STAGE

  const float linv = 1.0f / lrun;
  float lr4[4];
#pragma unroll
  for (int r = 0; r < 4; r++) lr4[r] = __shfl(linv, 4 * g + r);
  const int orow0 = qt * 64 + w * 16;
  float* op = out + base;
#pragma unroll
  for (int n = 0; n < 4; n++)
#pragma unroll
    for (int r = 0; r < 4; r++)
      op[(size_t)(orow0 + 4 * g + r) * D_ + 16 * n + lr] = Oacc[n][r] * lr4[r];
}

// ---------------- fallback attention (round-9 kernel, verbatim math) -------
__global__ __launch_bounds__(256, 2) void attn_mfma(
    const float* __restrict__ q, const float* __restrict__ k,
    const float* __restrict__ v, const unsigned long long* __restrict__ mask,
    float* __restrict__ out) {
  __shared__ unsigned short Kh[64 * 64], Kl[64 * 64];
  __shared__ unsigned short Vth[64 * 64], Vtl[64 * 64];
  __shared__ unsigned short Phs[4][1024], Pls[4][1024];

  const int bh = blockIdx.x, qt = blockIdx.y;
  const int b = bh >> 4;
  const int tid = threadIdx.x, w = tid >> 6, lane = tid & 63;
  const int lr = lane & 15;
  const int g = lane >> 4;
  const size_t base = (size_t)bh * (T_ * D_);
  const int qrow_g = qt * 64 + w * 16 + lr;
  const unsigned swz = ((unsigned)(lr & 7)) << 4;

  s16x8 qfh[2], qfl[2];
  {
    const float* qp = q + base + (size_t)qrow_g * D_;
#pragma unroll
    for (int ks = 0; ks < 2; ks++) {
      union { unsigned short us[8]; s16x8 v; } h, l;
#pragma unroll
      for (int e2 = 0; e2 < 2; e2++) {
        const float4 f = *(const float4*)(qp + 32 * ks + 8 * g + 4 * e2);
#pragma unroll
        for (int e = 0; e < 4; e++) {
          const float x = (&f.x)[e] * 0.125f;
          const unsigned short hh = f2bf(x);
          h.us[4 * e2 + e] = hh;
          l.us[4 * e2 + e] = f2bf(x - bf2f(hh));
        }
      }
      qfh[ks] = h.v; qfl[ks] = l.v;
    }
  }

  f32x4 Oacc[4];
#pragma unroll
  for (int n = 0; n < 4; n++) Oacc[n] = (f32x4){0.f, 0.f, 0.f, 0.f};
  float mrun = -INFINITY, lrun = 0.f;

  const unsigned long long* mrow = mask + ((size_t)(b * T_ + qrow_g) << 4);
  const int dv = tid & 63, k0v = (tid >> 6) * 16;

  float Kst[16], Vst[16], Kst2[16], Vst2[16];
  {
    const float4* kp4 = (const float4*)(k + base);
    const float* vp = v + base;
#pragma unroll
    for (int i = 0; i < 4; i++) {
      const float4 f = kp4[tid + 256 * i];
      Kst[4 * i + 0] = f.x; Kst[4 * i + 1] = f.y;
      Kst[4 * i + 2] = f.z; Kst[4 * i + 3] = f.w;
    }
#pragma unroll
    for (int j = 0; j < 16; j++) Vst[j] = vp[(size_t)(k0v + j) * D_ + dv];
  }
  unsigned long long mw = mrow[0];

  for (int kt = 0; kt <= qt; kt++) {
    __syncthreads();
#pragma unroll
    for (int i = 0; i < 4; i++) {
      const int flat4 = tid + 256 * i, key = flat4 >> 4, dq = flat4 & 15;
      union { unsigned short us[4]; uint2 d; } h, l;
#pragma unroll
      for (int e = 0; e < 4; e++) {
        const float x = Kst[4 * i + e];
        const unsigned short hh = f2bf(x);
        h.us[e] = hh; l.us[e] = f2bf(x - bf2f(hh));
      }
      const unsigned byte = (unsigned)(key * 128 + dq * 8) ^ (((unsigned)(key & 7)) << 4);
      *(uint2*)((char*)Kh + byte) = h.d;
      *(uint2*)((char*)Kl + byte) = l.d;
    }
#pragma unroll
    for (int i = 0; i < 2; i++) {
      union { unsigned short us[8]; uint4 q; } h, l;
#pragma unroll
      for (int j = 0; j < 8; j++) {
        const float x = Vst[8 * i + j];
        const unsigned short hh = f2bf(x);
        h.us[j] = hh; l.us[j] = f2bf(x - bf2f(hh));
      }
      const unsigned byte =
          (unsigned)(dv * 128 + (k0v + 8 * i) * 2) ^ (((unsigned)(dv & 7)) << 4);
      *(uint4*)((char*)Vth + byte) = h.q;
      *(uint4*)((char*)Vtl + byte) = l.q;
    }
    __syncthreads();

    const int ktn = (kt < qt) ? kt + 1 : qt;
    {
      const float4* kp4 = (const float4*)(k + base + (size_t)(ktn * 64) * D_);
      const float* vp = v + base + (size_t)(ktn * 64) * D_;
#pragma unroll
      for (int i = 0; i < 4; i++) {
        const float4 f = kp4[tid + 256 * i];
        Kst2[4 * i + 0] = f.x; Kst2[4 * i + 1] = f.y;
        Kst2[4 * i + 2] = f.z; Kst2[4 * i + 3] = f.w;
      }
#pragma unroll
      for (int j = 0; j < 16; j++) Vst2[j] = vp[(size_t)(k0v + j) * D_ + dv];
    }
    const unsigned long long mwn = mrow[ktn];

    if (__any(mw != 0ull)) {
      f32x4 S4[4];
#pragma unroll
      for (int m = 0; m < 4; m++) {
        f32x4 acc = (f32x4){0.f, 0.f, 0.f, 0.f};
#pragma unroll
        for (int ks = 0; ks < 2; ks++) {
          const unsigned byte =
              ((unsigned)((16 * m + lr) * 128 + 64 * ks + 16 * g)) ^ swz;
          const s16x8 kfh = *(const s16x8*)((const char*)Kh + byte);
          const s16x8 kfl = *(const s16x8*)((const char*)Kl + byte);
          acc = __builtin_amdgcn_mfma_f32_16x16x32_bf16(kfh, qfh[ks], acc, 0, 0, 0);
          acc = __builtin_amdgcn_mfma_f32_16x16x32_bf16(kfh, qfl[ks], acc, 0, 0, 0);
          acc = __builtin_amdgcn_mfma_f32_16x16x32_bf16(kfl, qfh[ks], acc, 0, 0, 0);
        }
        S4[m] = acc;
      }

      float sv[16]; unsigned okb = 0; float tmax = -INFINITY;
#pragma unroll
      for (int jj = 0; jj < 16; jj++) {
        const int bit = 16 * (jj >> 2) + 4 * g + (jj & 3);
        const bool ok = (mw >> bit) & 1ull;
        okb |= ((unsigned)ok) << jj;
        const float s = ok ? S4[jj >> 2][jj & 3] : -INFINITY;
        sv[jj] = s; tmax = fmaxf(tmax, s);
      }
      tmax = fmaxf(tmax, __shfl_xor(tmax, 16));
      tmax = fmaxf(tmax, __shfl_xor(tmax, 32));
      if (__any(tmax > mrun + 8.0f)) {
        const float mnew = fmaxf(mrun, tmax);
        const float corr = (mnew == -INFINITY) ? 1.0f : __expf(mrun - mnew);
        lrun *= corr; mrun = mnew;
        float cr[4];
#pragma unroll
        for (int r = 0; r < 4; r++) cr[r] = __shfl(corr, 4 * g + r);
#pragma unroll
        for (int n = 0; n < 4; n++)
#pragma unroll
          for (int r = 0; r < 4; r++) Oacc[n][r] *= cr[r];
      }
      float pj[16]; float lsum = 0.f;
#pragma unroll
      for (int jj = 0; jj < 16; jj++) {
        const float e = __expf(sv[jj] - mrun);
        const float pv = ((okb >> jj) & 1u) ? e : 0.f;
        pj[jj] = pv; lsum += pv;
      }
      lsum += __shfl_xor(lsum, 16);
      lsum += __shfl_xor(lsum, 32);
      lrun += lsum;

#pragma unroll
      for (int m = 0; m < 4; m++) {
        union { unsigned short us[4]; uint2 d; } h, l;
#pragma unroll
        for (int r = 0; r < 4; r++) {
          const float pv = pj[4 * m + r];
          const unsigned short hh = f2bf(pv);
          h.us[r] = hh; l.us[r] = f2bf(pv - bf2f(hh));
        }
        const unsigned byte =
            ((unsigned)(lr * 128 + (16 * m + 4 * g) * 2)) ^ swz;
        *(uint2*)((char*)Phs + 2048 * w + byte) = h.d;
        *(uint2*)((char*)Pls + 2048 * w + byte) = l.d;
      }
      asm volatile("s_waitcnt lgkmcnt(0)" ::: "memory");
      __builtin_amdgcn_sched_barrier(0);

#pragma unroll
      for (int ks = 0; ks < 2; ks++) {
        const unsigned pb = ((unsigned)(lr * 128 + 64 * ks + 16 * g)) ^ swz;
        const s16x8 pfh = *(const s16x8*)((const char*)Phs + 2048 * w + pb);
        const s16x8 pfl = *(const s16x8*)((const char*)Pls + 2048 * w + pb);
#pragma unroll
        for (int n = 0; n < 4; n++) {
          const unsigned vb =
              ((unsigned)((16 * n + lr) * 128 + 64 * ks + 16 * g)) ^ swz;
          const s16x8 vfh = *(const s16x8*)((const char*)Vth + vb);
          const s16x8 vfl = *(const s16x8*)((const char*)Vtl + vb);
          Oacc[n] = __builtin_amdgcn_mfma_f32_16x16x32_bf16(pfh, vfh, Oacc[n], 0, 0, 0);
          Oacc[n] = __builtin_amdgcn_mfma_f32_16x16x32_bf16(pfh, vfl, Oacc[n], 0, 0, 0);
          Oacc[n] = __builtin_amdgcn_mfma_f32_16x16x32_bf16(pfl, vfh, Oacc[n], 0, 0, 0);
        }
      }
    }

#pragma unroll
    for (int i = 0; i < 16; i++) { Kst[i] = Kst2[i]; Vst[i] = Vst2[i]; }
    mw = mwn;
  }

  const float linv = 1.0f / lrun;
  float lr4[4];
#pragma unroll
  for (int r = 0; r < 4; r++) lr4[r] = __shfl(linv, 4 * g + r);
  const int orow0 = qt * 64 + w * 16;
  float* op = out + base;
#pragma unroll
  for (int n = 0; n < 4; n++)
#pragma unroll
    for (int r = 0; r < 4; r++)
      op[(size_t)(orow0 + 4 * g + r) * D_ + 16 * n + lr] = Oacc[n][r] * lr4[r];
}

extern "C" void kernel_launch(void* const* d_in, const int* in_sizes, int n_in,
                              void* d_out, int out_size, void* d_ws, size_t ws_size,
                              hipStream_t stream) {
  const float* q  = (const float*)d_in[0];
  const float* k  = (const float*)d_in[1];
  const float* v  = (const float*)d_in[2];
  const float* W1 = (const float*)d_in[3];
  const float* b1 = (const float*)d_in[4];
  const float* W2 = (const float*)d_in[5];
  const float* b2 = (const float*)d_in[6];
  float* out = (float*)d_out;

  // ws: probs 256KB | mask 512KB | Khi,Klo,VThi,VTlo 8MB each (fast path)
  float* probs = (float*)d_ws;
  unsigned long long* mask = (unsigned long long*)((char*)d_ws + 262144);
  const size_t NEED = 786432ull + 4ull * 8388608ull;

  if (ws_size >= NEED) {
    unsigned short* khi  = (unsigned short*)((char*)d_ws + 786432);
    unsigned short* klo  = (unsigned short*)((char*)d_ws + 786432 + 8388608ull);
    unsigned short* vthi = (unsigned short*)((char*)d_ws + 786432 + 16777216ull);
    unsigned short* vtlo = (unsigned short*)((char*)d_ws + 786432 + 25165824ull);
    prep_kernel<<<1536, 256, 0, stream>>>(k, v, W1, b1, W2, b2, probs,
                                          khi, klo, vthi, vtlo);
    mask_v3<<<512, 256, 0, stream>>>(probs, mask);
    attn_bf16<<<1024, 256, 0, stream>>>(q, khi, klo, vthi, vtlo, mask, out);
  } else {
    prep_kernel<<<512, 256, 0, stream>>>(k, v, W1, b1, W2, b2, probs,
                                         nullptr, nullptr, nullptr, nullptr);
    mask_v3<<<512, 256, 0, stream>>>(probs, mask);
    attn_mfma<<<dim3(B_ * H_, T_ / 64), 256, 0, stream>>>(q, k, v, mask, out);
  }
}